// Round 3
// baseline (388.663 us; speedup 1.0000x reference)
//
#include <hip/hip_runtime.h>
#include <math.h>

// Problem constants (fixed by the reference)
#define SPATIAL (64*64*64)     // 262144 elements per (b, channel)
#define SPATIAL4 (SPATIAL/4)   // 65536 float4 per channel
#define EIGHTH4 (SPATIAL4/8)   // 8192 float4 per eighth-channel
#define NCH 64
#define NB 2
#define BN_EPS 1e-5f

// -------- Kernel 1: partial sums, 8 blocks per (tensor,b,channel) ----------
// 2048 blocks x 256 threads. Fully unrolled: 32 float4 loads/thread into 4
// independent accumulators -> many loads in flight (latency hiding).
__global__ __launch_bounds__(256) void mean_kernel(const float* __restrict__ g,
                                                   const float* __restrict__ x,
                                                   float* __restrict__ partial) {
    int blk = blockIdx.x;          // 0..2047
    int ch  = blk >> 3;            // 0..255 (0..127 = g channels, 128..255 = x)
    int e   = blk & 7;
    const float* src = (ch < 128)
        ? g + (size_t)ch * SPATIAL
        : x + (size_t)(ch - 128) * SPATIAL;
    const float4* s4 = (const float4*)src + (size_t)e * EIGHTH4;
    int tid = threadIdx.x;

    float4 a0 = make_float4(0.f,0.f,0.f,0.f), a1 = a0, a2 = a0, a3 = a0;
    #pragma unroll
    for (int it = 0; it < 8; ++it) {
        int base = it * 1024 + tid;
        float4 v0 = s4[base];
        float4 v1 = s4[base + 256];
        float4 v2 = s4[base + 512];
        float4 v3 = s4[base + 768];
        a0.x += v0.x; a0.y += v0.y; a0.z += v0.z; a0.w += v0.w;
        a1.x += v1.x; a1.y += v1.y; a1.z += v1.z; a1.w += v1.w;
        a2.x += v2.x; a2.y += v2.y; a2.z += v2.z; a2.w += v2.w;
        a3.x += v3.x; a3.y += v3.y; a3.z += v3.z; a3.w += v3.w;
    }
    float sum = ((a0.x + a0.y) + (a0.z + a0.w)) + ((a1.x + a1.y) + (a1.z + a1.w))
              + ((a2.x + a2.y) + (a2.z + a2.w)) + ((a3.x + a3.y) + (a3.z + a3.w));
    // wave reduce (wave = 64)
    #pragma unroll
    for (int off = 32; off > 0; off >>= 1)
        sum += __shfl_down(sum, off, 64);
    __shared__ float wsum[4];
    int lane = tid & 63, wave = tid >> 6;
    if (lane == 0) wsum[wave] = sum;
    __syncthreads();
    if (tid == 0)
        partial[blk] = wsum[0] + wsum[1] + wsum[2] + wsum[3];
}

// -------- Kernel 2: fold partials -> pooled, gating MLP -> 128 coefs -------
// 128 blocks (one per (b,gc)) x 64 threads (one per l). Coalesced w2 reads.
__global__ __launch_bounds__(64) void mlp_kernel(const float* __restrict__ partial,
                           const float* __restrict__ w1, const float* __restrict__ b1,
                           const float* __restrict__ w2, const float* __restrict__ b2,
                           const float* __restrict__ psi_w, const float* __restrict__ psi_b,
                           const float* __restrict__ bn_gamma, const float* __restrict__ bn_beta,
                           const float* __restrict__ bn_mean, const float* __restrict__ bn_var,
                           float* __restrict__ coef) {
    __shared__ float p[256];   // pooled, layout [b*128 + feature]
    __shared__ float h[32];    // hidden for this block's batch
    int tid = threadIdx.x;     // 0..63
    int blk = blockIdx.x;      // 0..127
    int b = blk >> 6, gc = blk & 63;

    // pooled: sum 8 partials per channel
    #pragma unroll
    for (int ch = tid; ch < 256; ch += 64) {
        const float* pp = partial + 8 * ch;
        float s = ((pp[0] + pp[1]) + (pp[2] + pp[3])) + ((pp[4] + pp[5]) + (pp[6] + pp[7]));
        int pi = (ch < 128) ? ((ch >> 6) * 128 + (ch & 63))
                            : (((ch - 128) >> 6) * 128 + 64 + ((ch - 128) & 63));
        p[pi] = s * (1.0f / SPATIAL);
    }
    __syncthreads();
    // hidden layer (redundant per block, cheap): threads 0..31
    if (tid < 32) {
        float acc = b1[tid];
        const float* wr = w1 + tid * 128;
        #pragma unroll 4
        for (int k = 0; k < 128; ++k) acc += p[b * 128 + k] * wr[k];
        h[tid] = fmaxf(acc, 0.f);
    }
    __syncthreads();
    // each thread: one l. w2 row contiguous 128B per lane, block reads 8KB.
    const float4* wr = (const float4*)(w2 + (size_t)(gc * 64 + tid) * 32);
    float z = b2[gc * 64 + tid];
    #pragma unroll
    for (int j = 0; j < 8; ++j) {
        float4 wv = wr[j];
        z += h[4*j] * wv.x + h[4*j+1] * wv.y + h[4*j+2] * wv.z + h[4*j+3] * wv.w;
    }
    float sig = 1.f / (1.f + expf(-z));   // dw[b,gc,l]
    float val = sig * psi_w[tid];
    #pragma unroll
    for (int off = 32; off > 0; off >>= 1)
        val += __shfl_down(val, off, 64);
    float scale = bn_gamma[0] * rsqrtf(bn_var[0] + BN_EPS);
    if (tid == 0) coef[b * 64 + gc] = val * scale;
    if (blk == 0 && tid == 0)
        coef[128] = (psi_b[0] - bn_mean[0]) * scale + bn_beta[0];
}

// -------- Kernel 3: s = sum_g g*c ; out = x * sigmoid(s + bias) ------------
// 2048 blocks x 256 threads (8 blocks/CU, 32 waves/CU). Each wave owns 64
// float4 positions and 16 g-channels (4 independent accumulators); the 4
// waves combine via LDS, then each wave writes its 16 x-channels.
__global__ __launch_bounds__(256) void apply_kernel(const float* __restrict__ g,
                                                    const float* __restrict__ x,
                                                    const float* __restrict__ coef,
                                                    float* __restrict__ out) {
    int t    = threadIdx.x;
    int pos  = t & 63;                        // float4 position within block tile
    int quad = t >> 6;                        // wave id 0..3 -> 16 channels each
    int blk  = blockIdx.x;                    // 0..2047
    int batch = blk >> 10;                    // 1024 blocks per batch
    int base4 = (blk & 1023) * 64 + pos;      // float4 index within channel
    size_t bOff = (size_t)batch * NCH * SPATIAL4;

    const float4* g4 = (const float4*)g;
    const float4* x4 = (const float4*)x;
    float4* o4 = (float4*)out;

    const float* cf = coef + batch * NCH + quad * 16;
    const float4* gq = g4 + bOff + (size_t)(quad * 16) * SPATIAL4 + base4;

    float4 a0 = make_float4(0.f,0.f,0.f,0.f), a1 = a0, a2 = a0, a3 = a0;
    #pragma unroll
    for (int c = 0; c < 16; c += 4) {
        float c0 = cf[c], c1 = cf[c+1], c2 = cf[c+2], c3 = cf[c+3];
        float4 v0 = gq[(size_t)(c+0) * SPATIAL4];
        float4 v1 = gq[(size_t)(c+1) * SPATIAL4];
        float4 v2 = gq[(size_t)(c+2) * SPATIAL4];
        float4 v3 = gq[(size_t)(c+3) * SPATIAL4];
        a0.x += v0.x*c0; a0.y += v0.y*c0; a0.z += v0.z*c0; a0.w += v0.w*c0;
        a1.x += v1.x*c1; a1.y += v1.y*c1; a1.z += v1.z*c1; a1.w += v1.w*c1;
        a2.x += v2.x*c2; a2.y += v2.y*c2; a2.z += v2.z*c2; a2.w += v2.w*c2;
        a3.x += v3.x*c3; a3.y += v3.y*c3; a3.z += v3.z*c3; a3.w += v3.w*c3;
    }
    float4 acc;
    acc.x = (a0.x + a1.x) + (a2.x + a3.x);
    acc.y = (a0.y + a1.y) + (a2.y + a3.y);
    acc.z = (a0.z + a1.z) + (a2.z + a3.z);
    acc.w = (a0.w + a1.w) + (a2.w + a3.w);

    __shared__ float4 red[4][64];
    if (quad != 0) red[quad][pos] = acc;
    __syncthreads();
    if (quad == 0) {
        float4 r1 = red[1][pos], r2 = red[2][pos], r3 = red[3][pos];
        float d = coef[128];
        float4 s;
        s.x = 1.f / (1.f + expf(-((acc.x + r1.x) + (r2.x + r3.x) + d)));
        s.y = 1.f / (1.f + expf(-((acc.y + r1.y) + (r2.y + r3.y) + d)));
        s.z = 1.f / (1.f + expf(-((acc.z + r1.z) + (r2.z + r3.z) + d)));
        s.w = 1.f / (1.f + expf(-((acc.w + r1.w) + (r2.w + r3.w) + d)));
        red[0][pos] = s;
    }
    __syncthreads();
    float4 s = red[0][pos];
    const float4* xq = x4 + bOff + (size_t)(quad * 16) * SPATIAL4 + base4;
    float4* oq = o4 + bOff + (size_t)(quad * 16) * SPATIAL4 + base4;
    #pragma unroll
    for (int l = 0; l < 16; ++l) {
        float4 xv = xq[(size_t)l * SPATIAL4];
        oq[(size_t)l * SPATIAL4] = make_float4(xv.x * s.x, xv.y * s.y, xv.z * s.z, xv.w * s.w);
    }
}

extern "C" void kernel_launch(void* const* d_in, const int* in_sizes, int n_in,
                              void* d_out, int out_size, void* d_ws, size_t ws_size,
                              hipStream_t stream) {
    const float* g        = (const float*)d_in[0];
    const float* x        = (const float*)d_in[1];
    const float* w1       = (const float*)d_in[2];
    const float* b1       = (const float*)d_in[3];
    const float* w2       = (const float*)d_in[4];
    const float* b2       = (const float*)d_in[5];
    const float* psi_w    = (const float*)d_in[6];
    const float* psi_b    = (const float*)d_in[7];
    const float* bn_gamma = (const float*)d_in[8];
    const float* bn_beta  = (const float*)d_in[9];
    const float* bn_mean  = (const float*)d_in[10];
    const float* bn_var   = (const float*)d_in[11];
    float* out = (float*)d_out;
    float* ws  = (float*)d_ws;

    float* partial = ws;         // 2048 floats
    float* coef    = ws + 2048;  // 129 floats

    mean_kernel<<<2048, 256, 0, stream>>>(g, x, partial);
    mlp_kernel<<<128, 64, 0, stream>>>(partial, w1, b1, w2, b2, psi_w, psi_b,
                                       bn_gamma, bn_beta, bn_mean, bn_var, coef);
    apply_kernel<<<2048, 256, 0, stream>>>(g, x, coef, out);
}